// Round 6
// baseline (269.677 us; speedup 1.0000x reference)
//
#include <hip/hip_runtime.h>

// ---------- constants ----------
#define Bsz   8192
#define Tlen  20
#define OUT_VAL_OFF  57344      // 8192*7 (floats)
#define OUT_MEM_OFF  65536      // +8192  (floats)

// ws layout (bytes)
#define WS_GI     0            // float[100*384]  gi_table[v][g]
#define WS_D1     153600       // float[8*2*2*64] conv1 lookup (bank-rotated)
#define WS_W2BH   161792       // ushort[64*256]  bf16-hi conv2 w [o2][i*4+dp]
#define WS_W2BL   194560       // ushort[64*256]  bf16-lo residual
#define WS_W3BH   227328       // ushort[128*256] bf16-hi conv3 w [o3][o2*4+p2]
#define WS_W3BL   292864       // ushort[128*256] bf16-lo residual
#define WS_WHF    686080       // legacy (unused)
#define WS_WTBH   882688       // ushort[512*256] bf16-hi head W1 [u][k]
#define WS_WTBL   1144832      // ushort[512*256] bf16-lo residual [u][k]
#define WS_LB     1406976      // float[512]  (bih+bhh)
#define WS_C2W    1409024      // float[16384]  legacy fp32 c2wT (unused)
#define WS_C2B    1474560      // float[64]
#define WS_C3W    1474816      // float[32768]  legacy fp32 c3wT (unused)
#define WS_C3B    1605888      // float[128]
#define WS_C1B    1606400      // float[64]
#define WS_BH     1606656      // float[384]  gru_bhh
#define WS_B1     1608192      // float[512]
#define WS_W2     1610240      // float[8*256]
#define WS_B2     1618432      // float[8]
#define WS_FLAG   1618464      // int
#define WS_WHB    1618496      // ushort[384*128] bf16 whh[g][k] (GRU MFMA B)
#define WS_LWTB   1716800      // ushort[512*256] bf16 lstm [g][k] k<128 wih else whh

#define GBLK   512             // blocks (16 samples each)
#define GROWS  16              // samples per block
#define PREP_TASKS 453768

// MFMA fragment types
using frag16 = __attribute__((ext_vector_type(8))) short;   // 8 bf16 (4 VGPRs)
using fragf4 = __attribute__((ext_vector_type(4))) float;   // 4 fp32

// ---------- helpers ----------
__device__ __forceinline__ float bf2f(unsigned short u){
    union { unsigned int i; float f; } v; v.i = ((unsigned int)u) << 16; return v.f;
}
__device__ __forceinline__ unsigned short f2bf(float f){
    union { float f; unsigned int i; } v; v.f = f;
    unsigned int x = v.i;
    return (unsigned short)((x + 0x7fffu + ((x >> 16) & 1u)) >> 16);
}
// truncation hi + RNE lo split (fp32 ~= hi + lo to 2^-17 rel)
__device__ __forceinline__ void f2bf2(float f, unsigned short &h, unsigned short &l){
    union { float f; unsigned int i; } u; u.f = f;
    h = (unsigned short)(u.i >> 16);
    union { unsigned int i; float f; } t; t.i = u.i & 0xffff0000u;
    l = f2bf(f - t.f);
}
__device__ __forceinline__ float sigm(float x){ return 1.0f / (1.0f + __expf(-x)); }
__device__ __forceinline__ float tanh_f(float x){ return 1.0f - 2.0f / (__expf(2.0f * x) + 1.0f); }

template<bool BF>
__device__ __forceinline__ float G(const void* p, int i){
    if (BF) return bf2f(((const unsigned short*)p)[i]);
    else    return ((const float*)p)[i];
}

// ======================================================================
// dtype sniff (verified across r1-13)
// ======================================================================
__global__ __launch_bounds__(256) void sniff_kernel(
    const unsigned short* __restrict__ we, int* __restrict__ flag)
{
    __shared__ int cnt;
    if (threadIdx.x == 0) cnt = 0;
    __syncthreads();
    int c = 0;
    for (int i = threadIdx.x; i < 2048; i += 256) {
        int e = (we[i] >> 7) & 0xFF;
        if (e >= 96 && e <= 160) c++;
    }
    atomicAdd(&cnt, c);
    __syncthreads();
    if (threadIdx.x == 0) *flag = (cnt >= 1792) ? 1 : 0;
}

// ======================================================================
// prep: canonicalize + fused/transposed tables. 453768 tasks.
// ======================================================================
template<bool BF>
__global__ __launch_bounds__(256) void prep_kernel(
    const int* __restrict__ flag,
    const void* word_emb, const void* gru_wih, const void* gru_bih,
    const void* col_emb, const void* obj_emb, const void* st_emb,
    const void* conv1_w, const void* conv1_b,
    const void* conv2_w, const void* conv2_b,
    const void* conv3_w, const void* conv3_b,
    const void* lstm_wih, const void* lstm_whh,
    const void* lstm_bih, const void* lstm_bhh,
    const void* actor_w1, const void* actor_b1,
    const void* actor_w2, const void* actor_b2,
    const void* critic_w1, const void* critic_b1,
    const void* critic_w2, const void* critic_b2,
    const void* gru_whh, const void* gru_bhh,
    float* __restrict__ ws0)
{
    if ((*flag != 0) != BF) return;
    int task = blockIdx.x * 256 + threadIdx.x;
    if (task >= PREP_TASKS) return;
    char* wsb = (char*)ws0;
    if (task < 38400) {
        int v = task / 384, g = task - v * 384;
        float acc = G<BF>(gru_bih, g);
        #pragma unroll
        for (int d = 0; d < 32; d++)
            acc += G<BF>(word_emb, v * 32 + d) * G<BF>(gru_wih, g * 32 + d);
        ((float*)(wsb + WS_GI))[task] = acc;
    } else if (task < 40448) {
        int i2 = task - 38400;
        int o = i2 & 63; int tkk = i2 >> 6;
        int kx = tkk & 1, ky = (tkk >> 1) & 1, t = tkk >> 2;
        int c = t & 1, ob = (t >> 1) & 1, s = (t >> 2) & 1;
        float acc = 0.f;
        #pragma unroll
        for (int i = 0; i < 48; i++) {
            float e;
            if (i < 16)      e = G<BF>(col_emb, c * 16 + i);
            else if (i < 32) e = G<BF>(obj_emb, ob * 16 + (i - 16));
            else             e = G<BF>(st_emb, s * 16 + (i - 32));
            acc += e * G<BF>(conv1_w, ((o * 48 + i) * 2 + ky) * 2 + kx);
        }
        ((float*)(wsb + WS_D1))[tkk * 64 + ((o + tkk) & 63)] = acc;  // rotated
    } else if (task < 171520) {
        int i3 = task - 40448;                 // head W1 bf16 hi/lo [u][k]
        int u = i3 >> 8, k = i3 & 255;
        float w = (u < 256) ? G<BF>(actor_w1, u * 256 + k)
                            : G<BF>(critic_w1, (u - 256) * 256 + k);
        unsigned short hi = f2bf(w);
        ((unsigned short*)(wsb + WS_WTBH))[i3] = hi;
        ((unsigned short*)(wsb + WS_WTBL))[i3] = f2bf(w - bf2f(hi));
    } else if (task < 172032) {
        int i = task - 171520;
        ((float*)(wsb + WS_LB))[i] = G<BF>(lstm_bih, i) + G<BF>(lstm_bhh, i);
    } else if (task < 188416) {
        int i = task - 172032;                 // legacy c2wT (unused)
        int o = i & 63, pp = (i >> 6) & 3, ii = i >> 8;
        ((float*)(wsb + WS_C2W))[i] = G<BF>(conv2_w, o * 256 + ii * 4 + pp);
    } else if (task < 188480) {
        int i = task - 188416;
        ((float*)(wsb + WS_C2B))[i] = G<BF>(conv2_b, i);
    } else if (task < 221248) {
        int i = task - 188480;                 // legacy c3wT (unused)
        int o = i & 127, kk = i >> 7;
        ((float*)(wsb + WS_C3W))[i] = G<BF>(conv3_w, o * 256 + kk);
    } else if (task < 221376) {
        int i = task - 221248;
        ((float*)(wsb + WS_C3B))[i] = G<BF>(conv3_b, i);
    } else if (task < 221440) {
        int i = task - 221376;
        ((float*)(wsb + WS_C1B))[i] = G<BF>(conv1_b, i);
    } else if (task < 221824) {
        int i = task - 221440;
        ((float*)(wsb + WS_BH))[i] = G<BF>(gru_bhh, i);
    } else if (task < 222336) {
        int i = task - 221824;
        ((float*)(wsb + WS_B1))[i] = (i < 256) ? G<BF>(actor_b1, i) : G<BF>(critic_b1, i - 256);
    } else if (task < 224384) {
        int i = task - 222336;
        int u = i >> 8, k = i & 255;
        ((float*)(wsb + WS_W2))[i] = (u < 7) ? G<BF>(actor_w2, u * 256 + k) : G<BF>(critic_w2, k);
    } else if (task < 224392) {
        int i = task - 224384;
        ((float*)(wsb + WS_B2))[i] = (i < 7) ? G<BF>(actor_b2, i) : G<BF>(critic_b2, 0);
    } else if (task < 273544) {
        int i = task - 224392;                 // WHB2: bf16 whh[g][k], row-major
        ((unsigned short*)(wsb + WS_WHB))[i] = f2bf(G<BF>(gru_whh, i));
    } else if (task < 404616) {
        int i = task - 273544;                 // LWTB: bf16 lstm [g][k]
        int g = i >> 8, k = i & 255;
        float v = (k < 128) ? G<BF>(lstm_wih, g * 128 + k)
                            : G<BF>(lstm_whh, g * 128 + (k - 128));
        ((unsigned short*)(wsb + WS_LWTB))[i] = f2bf(v);
    } else if (task < 421000) {
        int i = task - 404616;                 // conv2 w hi/lo [o2][i*4+dp]
        float w = G<BF>(conv2_w, i);
        unsigned short hi = f2bf(w);
        ((unsigned short*)(wsb + WS_W2BH))[i] = hi;
        ((unsigned short*)(wsb + WS_W2BL))[i] = f2bf(w - bf2f(hi));
    } else {
        int i = task - 421000;                 // conv3 w hi/lo [o3][o2*4+p2]
        float w = G<BF>(conv3_w, i);
        unsigned short hi = f2bf(w);
        ((unsigned short*)(wsb + WS_W3BH))[i] = hi;
        ((unsigned short*)(wsb + WS_W3BL))[i] = f2bf(w - bf2f(hi));
    }
}

// ======================================================================
// fused kernel v12: conv1/2/3 + LSTM + GRU scan + heads, one launch,
// 512 blocks x 512 threads x 16 samples.
//  - conv3 writes bf16 x directly into sEh (no mem_out round-trip)
//  - conv3 M=16 exactly (no padding waste vs the 8-sample conv kernel)
//  - GEMM2 single-pass, 512 threads (4/output + shfl_xor reduce)
//  - LDS ~64.5KB with phase overlays; 2 blocks/CU (grid-capped anyway)
// ======================================================================
#define GI_LOAD(dst, t) do {                                                  \
    _Pragma("unroll")                                                         \
    for (int rg_ = 0; rg_ < 4; rg_++) {                                       \
        int tok_ = sTok2[(m0 + rg_) * Tlen + (t)];                            \
        const float* gp_ = gi_table + tok_ * 384 + j;                         \
        dst[rg_ * 3 + 0] = gp_[0];                                            \
        dst[rg_ * 3 + 1] = gp_[128];                                          \
        dst[rg_ * 3 + 2] = gp_[256];                                          \
    }                                                                         \
} while (0)

#define GRU_STEP(SRD, SWR, GC, GN, T) do {                                    \
    frag16 Af_[4];                                                            \
    _Pragma("unroll")                                                         \
    for (int kc_ = 0; kc_ < 4; kc_++)                                         \
        Af_[kc_] = *(const frag16*)((SRD) + l16 * 136 + kc_ * 32 + quad * 8); \
    fragf4 aR_ = {0.f,0.f,0.f,0.f}, aZ_ = {0.f,0.f,0.f,0.f};                  \
    fragf4 aN_ = {0.f,0.f,0.f,0.f};                                           \
    _Pragma("unroll")                                                         \
    for (int kc_ = 0; kc_ < 4; kc_++) {                                       \
        aR_ = __builtin_amdgcn_mfma_f32_16x16x32_bf16(Af_[kc_], Bf0[kc_], aR_, 0, 0, 0); \
        aZ_ = __builtin_amdgcn_mfma_f32_16x16x32_bf16(Af_[kc_], Bf1[kc_], aZ_, 0, 0, 0); \
        aN_ = __builtin_amdgcn_mfma_f32_16x16x32_bf16(Af_[kc_], Bf2[kc_], aN_, 0, 0, 0); \
    }                                                                         \
    if ((T) < Tlen - 1) GI_LOAD(GN, (T) + 1);                                 \
    _Pragma("unroll")                                                         \
    for (int reg_ = 0; reg_ < 4; reg_++) {                                    \
        float rg2_ = sigm(GC[reg_*3+0] + aR_[reg_] + bh0);                    \
        float zg_  = sigm(GC[reg_*3+1] + aZ_[reg_] + bh1);                    \
        float ng_  = tanh_f(GC[reg_*3+2] + rg2_ * (aN_[reg_] + bh2));         \
        float hn_  = (1.f - zg_) * ng_ + zg_ * hpv[reg_];                     \
        unsigned short hb_ = f2bf(hn_);                                       \
        hpv[reg_] = bf2f(hb_);                                                \
        (SWR)[(m0 + reg_) * 136 + j] = hb_;                                   \
    }                                                                         \
    __syncthreads();                                                          \
} while (0)

__global__ __launch_bounds__(512, 4) void gru_head_kernel(
    const int* __restrict__ flag,
    const int* __restrict__ image,
    const int* __restrict__ text, const void* memory,
    const float* __restrict__ ws0,
    float* __restrict__ mem_out,
    float* __restrict__ out_lp, float* __restrict__ out_val)
{
    const char* wsb = (const char*)ws0;
    const unsigned short* whb2 = (const unsigned short*)(wsb + WS_WHB);
    const unsigned short* lwtb = (const unsigned short*)(wsb + WS_LWTB);
    const unsigned short* wtbh = (const unsigned short*)(wsb + WS_WTBH);
    const unsigned short* wtbl = (const unsigned short*)(wsb + WS_WTBL);
    const unsigned short* w2bh = (const unsigned short*)(wsb + WS_W2BH);
    const unsigned short* w2bl = (const unsigned short*)(wsb + WS_W2BL);
    const unsigned short* w3bh = (const unsigned short*)(wsb + WS_W3BH);
    const unsigned short* w3bl = (const unsigned short*)(wsb + WS_W3BL);
    const float* D1g      = (const float*)(wsb + WS_D1);
    const float* c1bF     = (const float*)(wsb + WS_C1B);
    const float* c2bF     = (const float*)(wsb + WS_C2B);
    const float* c3bF     = (const float*)(wsb + WS_C3B);
    const float* gi_table = (const float*)(wsb + WS_GI);
    const float* bhF      = (const float*)(wsb + WS_BH);
    const float* b1F      = (const float*)(wsb + WS_B1);
    const float* W2f      = (const float*)(wsb + WS_W2);
    const float* B2f      = (const float*)(wsb + WS_B2);
    const float* lbF      = (const float*)(wsb + WS_LB);

    // ---- LDS: persistent sEh/sEl + phase-overlaid region2 ----
    // region2 phases: conv {stt,sD1,sp1h/l; sA3 over sp1h front}
    //                 scan {sHtA,sHtB}  head {sHid[512][16]}
    __shared__ __align__(16) char sU[16896 + 45840];
    __shared__ float sScore[128];
    __shared__ int   sTok2[320];

    unsigned short* sEh = (unsigned short*)sU;               // [16][264] 8448B
    unsigned short* sEl = (unsigned short*)(sU + 8448);      // [16][264] 8448B
    char* R2 = sU + 16896;
    unsigned char*  stt  = (unsigned char*)R2;               // 784B
    float*          sD1  = (float*)(R2 + 784);               // 8192B
    unsigned short* sp1h = (unsigned short*)(R2 + 8976);     // [576][16] 18432B
    unsigned short* sp1l = (unsigned short*)(R2 + 27408);    // 18432B
    unsigned short* sA3h = (unsigned short*)(R2 + 8976);     // [16][264] over sp1h
    unsigned short* sA3l = (unsigned short*)(R2 + 17424);    // [16][264]
    unsigned short* sHtA = (unsigned short*)R2;              // [16][136]
    unsigned short* sHtB = (unsigned short*)(R2 + 4352);
    float*          sHid = (float*)R2;                       // [512][16] 32768B

    int tid = threadIdx.x;
    int rbase = blockIdx.x * GROWS;
    int b0 = rbase;
    int wave = tid >> 6, lane = tid & 63;
    int quad = lane >> 4, l16 = lane & 15;
    int j = wave * 16 + l16;
    int m0 = quad * 4;
    const bool bfin = (*flag != 0);
    const unsigned short* mem16 = (const unsigned short*)memory;
    const float*          memf  = (const float*)memory;

    // ---- phase 0: stage tokens, h (k>=128 of emb), stt, sD1 ----
    if (tid < 320) sTok2[tid] = text[rbase * Tlen + tid];
    for (int i = tid; i < 2048; i += 512) {
        int m = i >> 7, k = i & 127;
        float v = bfin ? bf2f(mem16[(rbase + m) * 256 + k])
                       : memf[(rbase + m) * 256 + k];
        sEh[m * 264 + 128 + k] = f2bf(v);
    }
    for (int i = tid; i < 2048; i += 512) sD1[i] = D1g[i];
    for (int i = tid; i < 784; i += 512) {
        int s = i / 49, p = i - s * 49;
        int base = ((b0 + s) * 49 + p) * 3;
        stt[i] = (unsigned char)(image[base + 1] | (image[base] << 1) | (image[base + 2] << 2));
    }
    __syncthreads();

    // ---- conv1 (rotated-D1 lookup) + relu + pool -> sp1 hi/lo ----
    for (int task = tid; task < 9216; task += 512) {
        int s = task & 15;
        int op = task >> 4;
        int o = op / 9, p = op - o * 9;
        int py = p / 3, px = p - py * 3;
        float bo = c1bF[o];
        float mx = 0.f;
        #pragma unroll
        for (int dy = 0; dy < 2; dy++)
        #pragma unroll
        for (int dx = 0; dx < 2; dx++) {
            int y = 2 * py + dy, x = 2 * px + dx;
            float sum = bo;
            #pragma unroll
            for (int ky = 0; ky < 2; ky++)
            #pragma unroll
            for (int kx = 0; kx < 2; kx++) {
                int t = stt[s * 49 + (y + ky) * 7 + (x + kx)];
                int tkk = t * 4 + ky * 2 + kx;
                sum += sD1[tkk * 64 + ((o + tkk) & 63)];
            }
            mx = fmaxf(mx, sum);
        }
        unsigned short h, l;
        f2bf2(mx, h, l);
        sp1h[op * 16 + s] = h;
        sp1l[op * 16 + s] = l;
    }
    __syncthreads();

    // ---- conv2 MFMA: M=64 (s,p2) x N=64 x K=256 ----
    {
        int Mt  = wave >> 1;
        int NtB = (wave & 1) * 2;
        int s_a = Mt * 4 + (l16 >> 2);
        int p2  = l16 & 3;
        int bp  = 3 * (p2 >> 1) + (p2 & 1);
        fragf4 acc0 = {0.f,0.f,0.f,0.f}, acc1 = {0.f,0.f,0.f,0.f};
        int u0 = (NtB * 16 + l16) * 256;
        int u1 = u0 + 16 * 256;
        #pragma unroll
        for (int kc = 0; kc < 8; kc++) {
            int k0 = kc * 32 + quad * 8;
            int i0 = k0 >> 2;
            const unsigned short* hp = sp1h + (i0 * 9 + bp) * 16 + s_a;
            const unsigned short* lp = sp1l + (i0 * 9 + bp) * 16 + s_a;
            frag16 Ah, Al;
            Ah[0] = (short)hp[0];   Ah[1] = (short)hp[16];
            Ah[2] = (short)hp[48];  Ah[3] = (short)hp[64];
            Ah[4] = (short)hp[144]; Ah[5] = (short)hp[160];
            Ah[6] = (short)hp[192]; Ah[7] = (short)hp[208];
            Al[0] = (short)lp[0];   Al[1] = (short)lp[16];
            Al[2] = (short)lp[48];  Al[3] = (short)lp[64];
            Al[4] = (short)lp[144]; Al[5] = (short)lp[160];
            Al[6] = (short)lp[192]; Al[7] = (short)lp[208];
            frag16 W0h = *(const frag16*)(w2bh + u0 + k0);
            frag16 W0l = *(const frag16*)(w2bl + u0 + k0);
            frag16 W1h = *(const frag16*)(w2bh + u1 + k0);
            frag16 W1l = *(const frag16*)(w2bl + u1 + k0);
            acc0 = __builtin_amdgcn_mfma_f32_16x16x32_bf16(Ah, W0h, acc0, 0, 0, 0);
            acc0 = __builtin_amdgcn_mfma_f32_16x16x32_bf16(Al, W0h, acc0, 0, 0, 0);
            acc0 = __builtin_amdgcn_mfma_f32_16x16x32_bf16(Ah, W0l, acc0, 0, 0, 0);
            acc1 = __builtin_amdgcn_mfma_f32_16x16x32_bf16(Ah, W1h, acc1, 0, 0, 0);
            acc1 = __builtin_amdgcn_mfma_f32_16x16x32_bf16(Al, W1h, acc1, 0, 0, 0);
            acc1 = __builtin_amdgcn_mfma_f32_16x16x32_bf16(Ah, W1l, acc1, 0, 0, 0);
        }
        __syncthreads();   // all sp1 reads done; sA3 overlays sp1h front
        int sC = Mt * 4 + quad;
        #pragma unroll
        for (int nt = 0; nt < 2; nt++) {
            fragf4 a = nt ? acc1 : acc0;
            int o2 = (NtB + nt) * 16 + l16;
            float b = c2bF[o2];
            #pragma unroll
            for (int reg = 0; reg < 4; reg++) {
                float v = fmaxf(a[reg] + b, 0.f);
                unsigned short h, l;
                f2bf2(v, h, l);
                sA3h[sC * 264 + o2 * 4 + reg] = h;
                sA3l[sC * 264 + o2 * 4 + reg] = l;
            }
        }
    }
    __syncthreads();

    // ---- conv3 MFMA: M=16 x N=128 x K=256; x -> sEh (bf16 RNE) ----
    {
        fragf4 acc0 = {0.f,0.f,0.f,0.f};
        int u0 = (wave * 16 + l16) * 256;
        #pragma unroll
        for (int kc = 0; kc < 8; kc++) {
            int k0 = kc * 32 + quad * 8;
            frag16 Ah = *(const frag16*)(sA3h + l16 * 264 + k0);
            frag16 Al = *(const frag16*)(sA3l + l16 * 264 + k0);
            frag16 W0h = *(const frag16*)(w3bh + u0 + k0);
            frag16 W0l = *(const frag16*)(w3bl + u0 + k0);
            acc0 = __builtin_amdgcn_mfma_f32_16x16x32_bf16(Ah, W0h, acc0, 0, 0, 0);
            acc0 = __builtin_amdgcn_mfma_f32_16x16x32_bf16(Al, W0h, acc0, 0, 0, 0);
            acc0 = __builtin_amdgcn_mfma_f32_16x16x32_bf16(Ah, W0l, acc0, 0, 0, 0);
        }
        int o3 = wave * 16 + l16;
        float b = c3bF[o3];
        #pragma unroll
        for (int reg = 0; reg < 4; reg++) {
            int s = quad * 4 + reg;
            sEh[s * 264 + o3] = f2bf(fmaxf(acc0[reg] + b, 0.f));
        }
    }
    __syncthreads();   // x + h staged in sEh

    // ---- LSTM MFMA: gates[16x512] = xa[16x256] @ lwtb^T ----
    {
        frag16 Ax[8];
        #pragma unroll
        for (int kc = 0; kc < 8; kc++)
            Ax[kc] = *(const frag16*)(sEh + l16 * 264 + kc * 32 + quad * 8);
        fragf4 aI = {0.f,0.f,0.f,0.f}, aF = {0.f,0.f,0.f,0.f};
        fragf4 aG = {0.f,0.f,0.f,0.f}, aO = {0.f,0.f,0.f,0.f};
        #pragma unroll
        for (int kc = 0; kc < 8; kc++) {
            int ko = kc * 32 + quad * 8;
            frag16 bI = *(const frag16*)(lwtb + (j)       * 256 + ko);
            frag16 bF = *(const frag16*)(lwtb + (128 + j) * 256 + ko);
            frag16 bG = *(const frag16*)(lwtb + (256 + j) * 256 + ko);
            frag16 bO = *(const frag16*)(lwtb + (384 + j) * 256 + ko);
            aI = __builtin_amdgcn_mfma_f32_16x16x32_bf16(Ax[kc], bI, aI, 0, 0, 0);
            aF = __builtin_amdgcn_mfma_f32_16x16x32_bf16(Ax[kc], bF, aF, 0, 0, 0);
            aG = __builtin_amdgcn_mfma_f32_16x16x32_bf16(Ax[kc], bG, aG, 0, 0, 0);
            aO = __builtin_amdgcn_mfma_f32_16x16x32_bf16(Ax[kc], bO, aO, 0, 0, 0);
        }
        float lbI = lbF[j], lbFg = lbF[128 + j], lbG = lbF[256 + j], lbO = lbF[384 + j];
        __syncthreads();   // all sEh (xa) fragment reads complete
        #pragma unroll
        for (int reg = 0; reg < 4; reg++) {
            int m = m0 + reg;
            float ig = sigm(aI[reg] + lbI);
            float fg = sigm(aF[reg] + lbFg);
            float gv = tanh_f(aG[reg] + lbG);
            float og = sigm(aO[reg] + lbO);
            float cv = bfin ? bf2f(mem16[(rbase + m) * 256 + 128 + j])
                            : memf[(rbase + m) * 256 + 128 + j];
            float cn = fg * cv + ig * gv;
            float hn = og * tanh_f(cn);
            mem_out[(rbase + m) * 256 + j]       = hn;
            mem_out[(rbase + m) * 256 + 128 + j] = cn;
            unsigned short hh = f2bf(hn);
            sEh[m * 264 + j] = hh;                      // emb hi, k<128
            sEl[m * 264 + j] = f2bf(hn - bf2f(hh));     // emb lo residual
        }
    }
    // zero sHt ping-pong (overlays dead conv scratch)
    for (int i = tid; i < 2176; i += 512) { sHtA[i] = 0; sHtB[i] = 0; }

    // ---- GRU B-frags (resident across scan; VGPR cap 128 keeps them) ----
    frag16 Bf0[4], Bf1[4], Bf2[4];
    #pragma unroll
    for (int kc = 0; kc < 4; kc++) {
        int ko = kc * 32 + quad * 8;
        Bf0[kc] = *(const frag16*)(whb2 + (j)       * 128 + ko);
        Bf1[kc] = *(const frag16*)(whb2 + (128 + j) * 128 + ko);
        Bf2[kc] = *(const frag16*)(whb2 + (256 + j) * 128 + ko);
    }
    float bh0 = bhF[j], bh1 = bhF[128 + j], bh2 = bhF[256 + j];
    float hpv[4] = { 0.f, 0.f, 0.f, 0.f };
    float ga[12], gb[12];

    GI_LOAD(ga, 0);
    __syncthreads();   // sHt zeros visible before first A-frag read

    // ---- scan: 1 barrier/step, ping-pong sHt, gi prefetched across barrier ----
    for (int tt = 0; tt < 10; tt++) {
        int t0 = tt * 2;
        GRU_STEP(sHtA, sHtB, ga, gb, t0);
        GRU_STEP(sHtB, sHtA, gb, ga, t0 + 1);
    }

    // ---- emb stage k>=128: gru h from regs (exact bf16; El zero there) ----
    #pragma unroll
    for (int reg = 0; reg < 4; reg++) {
        int m = m0 + reg;
        sEh[m * 264 + 128 + j] = f2bf(hpv[reg]);
    }
    __syncthreads();

    // ---- head GEMM1 on MFMA: bf16 hi+lo split; El-skip for k>=128 ----
    fragf4 acc[4];
    {
        fragf4 z4 = {0.f,0.f,0.f,0.f};
        #pragma unroll
        for (int jb = 0; jb < 4; jb++) acc[jb] = z4;
        #pragma unroll
        for (int kc = 0; kc < 8; kc++) {
            int ko = kc * 32 + quad * 8;
            frag16 Eh = *(const frag16*)(sEh + l16 * 264 + ko);
            #pragma unroll
            for (int jb = 0; jb < 4; jb++) {
                int u = jb * 128 + wave * 16 + l16;
                frag16 Wh = *(const frag16*)(wtbh + u * 256 + ko);
                frag16 Wl = *(const frag16*)(wtbl + u * 256 + ko);
                acc[jb] = __builtin_amdgcn_mfma_f32_16x16x32_bf16(Eh, Wh, acc[jb], 0, 0, 0);
                acc[jb] = __builtin_amdgcn_mfma_f32_16x16x32_bf16(Eh, Wl, acc[jb], 0, 0, 0);
            }
            if (kc < 4) {
                frag16 El = *(const frag16*)(sEl + l16 * 264 + ko);
                #pragma unroll
                for (int jb = 0; jb < 4; jb++) {
                    int u = jb * 128 + wave * 16 + l16;
                    frag16 Wh = *(const frag16*)(wtbh + u * 256 + ko);
                    acc[jb] = __builtin_amdgcn_mfma_f32_16x16x32_bf16(El, Wh, acc[jb], 0, 0, 0);
                }
            }
        }
    }
    __syncthreads();   // sHt/conv scratch dead; sHid overlay becomes live

    // ---- write hidden [512u][16m] swizzled ----
    #pragma unroll
    for (int jb = 0; jb < 4; jb++) {
        int u = jb * 128 + wave * 16 + l16;
        float bu = b1F[u];
        #pragma unroll
        for (int reg = 0; reg < 4; reg++) {
            int m = m0 + reg;
            sHid[u * 16 + ((m + l16) & 15)] = tanh_f(acc[jb][reg] + bu);
        }
    }
    __syncthreads();

    // ---- GEMM2: 512 threads, 4 per output (r,i); shfl_xor reduce ----
    {
        int out = tid >> 2, kq = tid & 3;
        int r = out >> 3, i = out & 7;
        const float* wrp = W2f + i * 256;
        int ubase = (i < 7) ? 0 : 256;
        float ps = 0.f;
        int kb = kq * 64;
        for (int kk = 0; kk < 64; kk++) {
            int u = ubase + kb + kk;
            ps += wrp[kb + kk] * sHid[u * 16 + ((r + (u & 15)) & 15)];
        }
        ps += __shfl_xor(ps, 1);
        ps += __shfl_xor(ps, 2);
        if (kq == 0) sScore[out] = ps + B2f[i];
    }
    __syncthreads();

    // ---- softmax + outputs (128 threads) ----
    if (tid < 128) {
        int r = tid >> 3, i = tid & 7;
        float sc = sScore[tid];
        const float* sr = sScore + r * 8;
        float mx = sr[0];
        #pragma unroll
        for (int a = 1; a < 7; a++) mx = fmaxf(mx, sr[a]);
        float se = 0.f;
        #pragma unroll
        for (int a = 0; a < 7; a++) se += __expf(sr[a] - mx);
        float lse = mx + __logf(se);
        if (i < 7) out_lp[(rbase + r) * 7 + i] = sc - lse;
        else       out_val[rbase + r] = sc;
    }
}

// ======================================================================
extern "C" void kernel_launch(void* const* d_in, const int* in_sizes, int n_in,
                              void* d_out, int out_size, void* d_ws, size_t ws_size,
                              hipStream_t stream) {
    const int*  image  = (const int*)d_in[0];
    const void* memory = d_in[1];
    const int*  text   = (const int*)d_in[2];

    char* wsb = (char*)d_ws;
    float* ws0  = (float*)wsb;
    int*   flag = (int*)(wsb + WS_FLAG);

    float* out = (float*)d_out;
    float* out_lp  = out;
    float* out_val = out + OUT_VAL_OFF;
    float* mem_out = out + OUT_MEM_OFF;

    sniff_kernel<<<1, 256, 0, stream>>>((const unsigned short*)d_in[16], flag);

    const int PREP_GRID = (PREP_TASKS + 255) / 256;
    prep_kernel<true><<<PREP_GRID, 256, 0, stream>>>(flag,
        d_in[16], d_in[17], d_in[19], d_in[4], d_in[3], d_in[5],
        d_in[6], d_in[7], d_in[8], d_in[9], d_in[10], d_in[11],
        d_in[12], d_in[13], d_in[14], d_in[15],
        d_in[21], d_in[22], d_in[23], d_in[24],
        d_in[25], d_in[26], d_in[27], d_in[28],
        d_in[18], d_in[20], ws0);
    prep_kernel<false><<<PREP_GRID, 256, 0, stream>>>(flag,
        d_in[16], d_in[17], d_in[19], d_in[4], d_in[3], d_in[5],
        d_in[6], d_in[7], d_in[8], d_in[9], d_in[10], d_in[11],
        d_in[12], d_in[13], d_in[14], d_in[15],
        d_in[21], d_in[22], d_in[23], d_in[24],
        d_in[25], d_in[26], d_in[27], d_in[28],
        d_in[18], d_in[20], ws0);

    gru_head_kernel<<<GBLK, 512, 0, stream>>>(flag, image, text, memory, ws0,
                                              mem_out, out_lp, out_val);
}

// Round 7
// 262.536 us; speedup vs baseline: 1.0272x; 1.0272x over previous
//
#include <hip/hip_runtime.h>

// ---------- constants ----------
#define Bsz   8192
#define Tlen  20
#define OUT_VAL_OFF  57344      // 8192*7 (floats)
#define OUT_MEM_OFF  65536      // +8192  (floats)

// ws layout (bytes)
#define WS_GI     0            // float[100*384]  gi_table[v][g]
#define WS_D1     153600       // float[8*2*2*64] conv1 lookup (bank-rotated)
#define WS_W2BH   161792       // ushort[64*256]  bf16-hi conv2 w [o2][i*4+dp]
#define WS_W2BL   194560       // ushort[64*256]  bf16-lo residual
#define WS_W3BH   227328       // ushort[128*256] bf16-hi conv3 w [o3][o2*4+p2]
#define WS_W3BL   292864       // ushort[128*256] bf16-lo residual
#define WS_WHF    686080       // legacy (unused)
#define WS_WTBH   882688       // ushort[512*256] bf16-hi head W1 [u][k]
#define WS_WTBL   1144832      // ushort[512*256] bf16-lo residual [u][k]
#define WS_LB     1406976      // float[512]  (bih+bhh)
#define WS_C2W    1409024      // float[16384]  legacy fp32 c2wT (unused)
#define WS_C2B    1474560      // float[64]
#define WS_C3W    1474816      // float[32768]  legacy fp32 c3wT (unused)
#define WS_C3B    1605888      // float[128]
#define WS_C1B    1606400      // float[64]
#define WS_BH     1606656      // float[384]  gru_bhh
#define WS_B1     1608192      // float[512]
#define WS_W2     1610240      // float[8*256]
#define WS_B2     1618432      // float[8]
#define WS_FLAG   1618464      // int
#define WS_WHB    1618496      // ushort[384*128] bf16 whh[g][k] (GRU MFMA B)
#define WS_LWTB   1716800      // ushort[512*256] bf16 lstm [g][k] k<128 wih else whh

#define GBLK   512             // blocks (16 samples each)
#define GROWS  16              // samples per block
#define PREP_TASKS 453768

// phase fence: nothing may be scheduled across (stops weight-load hoisting
// that inflated cross-phase liveness -> 55MB scratch spill in round 6)
#define PHASE_FENCE() __builtin_amdgcn_sched_barrier(0)

// MFMA fragment types
using frag16 = __attribute__((ext_vector_type(8))) short;   // 8 bf16 (4 VGPRs)
using fragf4 = __attribute__((ext_vector_type(4))) float;   // 4 fp32

// ---------- helpers ----------
__device__ __forceinline__ float bf2f(unsigned short u){
    union { unsigned int i; float f; } v; v.i = ((unsigned int)u) << 16; return v.f;
}
__device__ __forceinline__ unsigned short f2bf(float f){
    union { float f; unsigned int i; } v; v.f = f;
    unsigned int x = v.i;
    return (unsigned short)((x + 0x7fffu + ((x >> 16) & 1u)) >> 16);
}
// truncation hi + RNE lo split (fp32 ~= hi + lo to 2^-17 rel)
__device__ __forceinline__ void f2bf2(float f, unsigned short &h, unsigned short &l){
    union { float f; unsigned int i; } u; u.f = f;
    h = (unsigned short)(u.i >> 16);
    union { unsigned int i; float f; } t; t.i = u.i & 0xffff0000u;
    l = f2bf(f - t.f);
}
__device__ __forceinline__ float sigm(float x){ return 1.0f / (1.0f + __expf(-x)); }
__device__ __forceinline__ float tanh_f(float x){ return 1.0f - 2.0f / (__expf(2.0f * x) + 1.0f); }

template<bool BF>
__device__ __forceinline__ float G(const void* p, int i){
    if (BF) return bf2f(((const unsigned short*)p)[i]);
    else    return ((const float*)p)[i];
}

// ======================================================================
// dtype sniff (verified across r1-13)
// ======================================================================
__global__ __launch_bounds__(256) void sniff_kernel(
    const unsigned short* __restrict__ we, int* __restrict__ flag)
{
    __shared__ int cnt;
    if (threadIdx.x == 0) cnt = 0;
    __syncthreads();
    int c = 0;
    for (int i = threadIdx.x; i < 2048; i += 256) {
        int e = (we[i] >> 7) & 0xFF;
        if (e >= 96 && e <= 160) c++;
    }
    atomicAdd(&cnt, c);
    __syncthreads();
    if (threadIdx.x == 0) *flag = (cnt >= 1792) ? 1 : 0;
}

// ======================================================================
// prep: canonicalize + fused/transposed tables. 453768 tasks.
// ======================================================================
template<bool BF>
__global__ __launch_bounds__(256) void prep_kernel(
    const int* __restrict__ flag,
    const void* word_emb, const void* gru_wih, const void* gru_bih,
    const void* col_emb, const void* obj_emb, const void* st_emb,
    const void* conv1_w, const void* conv1_b,
    const void* conv2_w, const void* conv2_b,
    const void* conv3_w, const void* conv3_b,
    const void* lstm_wih, const void* lstm_whh,
    const void* lstm_bih, const void* lstm_bhh,
    const void* actor_w1, const void* actor_b1,
    const void* actor_w2, const void* actor_b2,
    const void* critic_w1, const void* critic_b1,
    const void* critic_w2, const void* critic_b2,
    const void* gru_whh, const void* gru_bhh,
    float* __restrict__ ws0)
{
    if ((*flag != 0) != BF) return;
    int task = blockIdx.x * 256 + threadIdx.x;
    if (task >= PREP_TASKS) return;
    char* wsb = (char*)ws0;
    if (task < 38400) {
        int v = task / 384, g = task - v * 384;
        float acc = G<BF>(gru_bih, g);
        #pragma unroll
        for (int d = 0; d < 32; d++)
            acc += G<BF>(word_emb, v * 32 + d) * G<BF>(gru_wih, g * 32 + d);
        ((float*)(wsb + WS_GI))[task] = acc;
    } else if (task < 40448) {
        int i2 = task - 38400;
        int o = i2 & 63; int tkk = i2 >> 6;
        int kx = tkk & 1, ky = (tkk >> 1) & 1, t = tkk >> 2;
        int c = t & 1, ob = (t >> 1) & 1, s = (t >> 2) & 1;
        float acc = 0.f;
        #pragma unroll
        for (int i = 0; i < 48; i++) {
            float e;
            if (i < 16)      e = G<BF>(col_emb, c * 16 + i);
            else if (i < 32) e = G<BF>(obj_emb, ob * 16 + (i - 16));
            else             e = G<BF>(st_emb, s * 16 + (i - 32));
            acc += e * G<BF>(conv1_w, ((o * 48 + i) * 2 + ky) * 2 + kx);
        }
        ((float*)(wsb + WS_D1))[tkk * 64 + ((o + tkk) & 63)] = acc;  // rotated
    } else if (task < 171520) {
        int i3 = task - 40448;                 // head W1 bf16 hi/lo [u][k]
        int u = i3 >> 8, k = i3 & 255;
        float w = (u < 256) ? G<BF>(actor_w1, u * 256 + k)
                            : G<BF>(critic_w1, (u - 256) * 256 + k);
        unsigned short hi = f2bf(w);
        ((unsigned short*)(wsb + WS_WTBH))[i3] = hi;
        ((unsigned short*)(wsb + WS_WTBL))[i3] = f2bf(w - bf2f(hi));
    } else if (task < 172032) {
        int i = task - 171520;
        ((float*)(wsb + WS_LB))[i] = G<BF>(lstm_bih, i) + G<BF>(lstm_bhh, i);
    } else if (task < 188416) {
        int i = task - 172032;                 // legacy c2wT (unused)
        int o = i & 63, pp = (i >> 6) & 3, ii = i >> 8;
        ((float*)(wsb + WS_C2W))[i] = G<BF>(conv2_w, o * 256 + ii * 4 + pp);
    } else if (task < 188480) {
        int i = task - 188416;
        ((float*)(wsb + WS_C2B))[i] = G<BF>(conv2_b, i);
    } else if (task < 221248) {
        int i = task - 188480;                 // legacy c3wT (unused)
        int o = i & 127, kk = i >> 7;
        ((float*)(wsb + WS_C3W))[i] = G<BF>(conv3_w, o * 256 + kk);
    } else if (task < 221376) {
        int i = task - 221248;
        ((float*)(wsb + WS_C3B))[i] = G<BF>(conv3_b, i);
    } else if (task < 221440) {
        int i = task - 221376;
        ((float*)(wsb + WS_C1B))[i] = G<BF>(conv1_b, i);
    } else if (task < 221824) {
        int i = task - 221440;
        ((float*)(wsb + WS_BH))[i] = G<BF>(gru_bhh, i);
    } else if (task < 222336) {
        int i = task - 221824;
        ((float*)(wsb + WS_B1))[i] = (i < 256) ? G<BF>(actor_b1, i) : G<BF>(critic_b1, i - 256);
    } else if (task < 224384) {
        int i = task - 222336;
        int u = i >> 8, k = i & 255;
        ((float*)(wsb + WS_W2))[i] = (u < 7) ? G<BF>(actor_w2, u * 256 + k) : G<BF>(critic_w2, k);
    } else if (task < 224392) {
        int i = task - 224384;
        ((float*)(wsb + WS_B2))[i] = (i < 7) ? G<BF>(actor_b2, i) : G<BF>(critic_b2, 0);
    } else if (task < 273544) {
        int i = task - 224392;                 // WHB2: bf16 whh[g][k], row-major
        ((unsigned short*)(wsb + WS_WHB))[i] = f2bf(G<BF>(gru_whh, i));
    } else if (task < 404616) {
        int i = task - 273544;                 // LWTB: bf16 lstm [g][k]
        int g = i >> 8, k = i & 255;
        float v = (k < 128) ? G<BF>(lstm_wih, g * 128 + k)
                            : G<BF>(lstm_whh, g * 128 + (k - 128));
        ((unsigned short*)(wsb + WS_LWTB))[i] = f2bf(v);
    } else if (task < 421000) {
        int i = task - 404616;                 // conv2 w hi/lo [o2][i*4+dp]
        float w = G<BF>(conv2_w, i);
        unsigned short hi = f2bf(w);
        ((unsigned short*)(wsb + WS_W2BH))[i] = hi;
        ((unsigned short*)(wsb + WS_W2BL))[i] = f2bf(w - bf2f(hi));
    } else {
        int i = task - 421000;                 // conv3 w hi/lo [o3][o2*4+p2]
        float w = G<BF>(conv3_w, i);
        unsigned short hi = f2bf(w);
        ((unsigned short*)(wsb + WS_W3BH))[i] = hi;
        ((unsigned short*)(wsb + WS_W3BL))[i] = f2bf(w - bf2f(hi));
    }
}

// ======================================================================
// fused kernel v13: v12 + PHASE_FENCE() at conv2->conv3, conv3->LSTM and
// LSTM->scan boundaries. Round-6 counters showed 55MB symmetric
// scratch traffic: the scheduler hoisted later-phase weight loads
// (Bf/lwtb/w3) into the conv phases, pushing liveness past the 128-reg
// cap. Fences cap each phase at its own (proven round-5) footprint.
// ======================================================================
#define GI_LOAD(dst, t) do {                                                  \
    _Pragma("unroll")                                                         \
    for (int rg_ = 0; rg_ < 4; rg_++) {                                       \
        int tok_ = sTok2[(m0 + rg_) * Tlen + (t)];                            \
        const float* gp_ = gi_table + tok_ * 384 + j;                         \
        dst[rg_ * 3 + 0] = gp_[0];                                            \
        dst[rg_ * 3 + 1] = gp_[128];                                          \
        dst[rg_ * 3 + 2] = gp_[256];                                          \
    }                                                                         \
} while (0)

#define GRU_STEP(SRD, SWR, GC, GN, T) do {                                    \
    frag16 Af_[4];                                                            \
    _Pragma("unroll")                                                         \
    for (int kc_ = 0; kc_ < 4; kc_++)                                         \
        Af_[kc_] = *(const frag16*)((SRD) + l16 * 136 + kc_ * 32 + quad * 8); \
    fragf4 aR_ = {0.f,0.f,0.f,0.f}, aZ_ = {0.f,0.f,0.f,0.f};                  \
    fragf4 aN_ = {0.f,0.f,0.f,0.f};                                           \
    _Pragma("unroll")                                                         \
    for (int kc_ = 0; kc_ < 4; kc_++) {                                       \
        aR_ = __builtin_amdgcn_mfma_f32_16x16x32_bf16(Af_[kc_], Bf0[kc_], aR_, 0, 0, 0); \
        aZ_ = __builtin_amdgcn_mfma_f32_16x16x32_bf16(Af_[kc_], Bf1[kc_], aZ_, 0, 0, 0); \
        aN_ = __builtin_amdgcn_mfma_f32_16x16x32_bf16(Af_[kc_], Bf2[kc_], aN_, 0, 0, 0); \
    }                                                                         \
    if ((T) < Tlen - 1) GI_LOAD(GN, (T) + 1);                                 \
    _Pragma("unroll")                                                         \
    for (int reg_ = 0; reg_ < 4; reg_++) {                                    \
        float rg2_ = sigm(GC[reg_*3+0] + aR_[reg_] + bh0);                    \
        float zg_  = sigm(GC[reg_*3+1] + aZ_[reg_] + bh1);                    \
        float ng_  = tanh_f(GC[reg_*3+2] + rg2_ * (aN_[reg_] + bh2));         \
        float hn_  = (1.f - zg_) * ng_ + zg_ * hpv[reg_];                     \
        unsigned short hb_ = f2bf(hn_);                                       \
        hpv[reg_] = bf2f(hb_);                                                \
        (SWR)[(m0 + reg_) * 136 + j] = hb_;                                   \
    }                                                                         \
    __syncthreads();                                                          \
} while (0)

__global__ __launch_bounds__(512, 4) void gru_head_kernel(
    const int* __restrict__ flag,
    const int* __restrict__ image,
    const int* __restrict__ text, const void* memory,
    const float* __restrict__ ws0,
    float* __restrict__ mem_out,
    float* __restrict__ out_lp, float* __restrict__ out_val)
{
    const char* wsb = (const char*)ws0;
    const unsigned short* whb2 = (const unsigned short*)(wsb + WS_WHB);
    const unsigned short* lwtb = (const unsigned short*)(wsb + WS_LWTB);
    const unsigned short* wtbh = (const unsigned short*)(wsb + WS_WTBH);
    const unsigned short* wtbl = (const unsigned short*)(wsb + WS_WTBL);
    const unsigned short* w2bh = (const unsigned short*)(wsb + WS_W2BH);
    const unsigned short* w2bl = (const unsigned short*)(wsb + WS_W2BL);
    const unsigned short* w3bh = (const unsigned short*)(wsb + WS_W3BH);
    const unsigned short* w3bl = (const unsigned short*)(wsb + WS_W3BL);
    const float* D1g      = (const float*)(wsb + WS_D1);
    const float* c1bF     = (const float*)(wsb + WS_C1B);
    const float* c2bF     = (const float*)(wsb + WS_C2B);
    const float* c3bF     = (const float*)(wsb + WS_C3B);
    const float* gi_table = (const float*)(wsb + WS_GI);
    const float* bhF      = (const float*)(wsb + WS_BH);
    const float* b1F      = (const float*)(wsb + WS_B1);
    const float* W2f      = (const float*)(wsb + WS_W2);
    const float* B2f      = (const float*)(wsb + WS_B2);
    const float* lbF      = (const float*)(wsb + WS_LB);

    // ---- LDS: persistent sEh/sEl + phase-overlaid region2 ----
    __shared__ __align__(16) char sU[16896 + 45840];
    __shared__ float sScore[128];
    __shared__ int   sTok2[320];

    unsigned short* sEh = (unsigned short*)sU;               // [16][264] 8448B
    unsigned short* sEl = (unsigned short*)(sU + 8448);      // [16][264] 8448B
    char* R2 = sU + 16896;
    unsigned char*  stt  = (unsigned char*)R2;               // 784B
    float*          sD1  = (float*)(R2 + 784);               // 8192B
    unsigned short* sp1h = (unsigned short*)(R2 + 8976);     // [576][16] 18432B
    unsigned short* sp1l = (unsigned short*)(R2 + 27408);    // 18432B
    unsigned short* sA3h = (unsigned short*)(R2 + 8976);     // [16][264] over sp1h
    unsigned short* sA3l = (unsigned short*)(R2 + 17424);    // [16][264]
    unsigned short* sHtA = (unsigned short*)R2;              // [16][136]
    unsigned short* sHtB = (unsigned short*)(R2 + 4352);
    float*          sHid = (float*)R2;                       // [512][16] 32768B

    int tid = threadIdx.x;
    int rbase = blockIdx.x * GROWS;
    int b0 = rbase;
    int wave = tid >> 6, lane = tid & 63;
    int quad = lane >> 4, l16 = lane & 15;
    int j = wave * 16 + l16;
    int m0 = quad * 4;
    const bool bfin = (*flag != 0);
    const unsigned short* mem16 = (const unsigned short*)memory;
    const float*          memf  = (const float*)memory;

    // ---- phase 0: stage tokens, h (k>=128 of emb), stt, sD1 ----
    if (tid < 320) sTok2[tid] = text[rbase * Tlen + tid];
    for (int i = tid; i < 2048; i += 512) {
        int m = i >> 7, k = i & 127;
        float v = bfin ? bf2f(mem16[(rbase + m) * 256 + k])
                       : memf[(rbase + m) * 256 + k];
        sEh[m * 264 + 128 + k] = f2bf(v);
    }
    for (int i = tid; i < 2048; i += 512) sD1[i] = D1g[i];
    for (int i = tid; i < 784; i += 512) {
        int s = i / 49, p = i - s * 49;
        int base = ((b0 + s) * 49 + p) * 3;
        stt[i] = (unsigned char)(image[base + 1] | (image[base] << 1) | (image[base + 2] << 2));
    }
    __syncthreads();

    // ---- conv1 (rotated-D1 lookup) + relu + pool -> sp1 hi/lo ----
    for (int task = tid; task < 9216; task += 512) {
        int s = task & 15;
        int op = task >> 4;
        int o = op / 9, p = op - o * 9;
        int py = p / 3, px = p - py * 3;
        float bo = c1bF[o];
        float mx = 0.f;
        #pragma unroll
        for (int dy = 0; dy < 2; dy++)
        #pragma unroll
        for (int dx = 0; dx < 2; dx++) {
            int y = 2 * py + dy, x = 2 * px + dx;
            float sum = bo;
            #pragma unroll
            for (int ky = 0; ky < 2; ky++)
            #pragma unroll
            for (int kx = 0; kx < 2; kx++) {
                int t = stt[s * 49 + (y + ky) * 7 + (x + kx)];
                int tkk = t * 4 + ky * 2 + kx;
                sum += sD1[tkk * 64 + ((o + tkk) & 63)];
            }
            mx = fmaxf(mx, sum);
        }
        unsigned short h, l;
        f2bf2(mx, h, l);
        sp1h[op * 16 + s] = h;
        sp1l[op * 16 + s] = l;
    }
    __syncthreads();

    // ---- conv2 MFMA: M=64 (s,p2) x N=64 x K=256 ----
    {
        int Mt  = wave >> 1;
        int NtB = (wave & 1) * 2;
        int s_a = Mt * 4 + (l16 >> 2);
        int p2  = l16 & 3;
        int bp  = 3 * (p2 >> 1) + (p2 & 1);
        fragf4 acc0 = {0.f,0.f,0.f,0.f}, acc1 = {0.f,0.f,0.f,0.f};
        int u0 = (NtB * 16 + l16) * 256;
        int u1 = u0 + 16 * 256;
        #pragma unroll
        for (int kc = 0; kc < 8; kc++) {
            int k0 = kc * 32 + quad * 8;
            int i0 = k0 >> 2;
            const unsigned short* hp = sp1h + (i0 * 9 + bp) * 16 + s_a;
            const unsigned short* lp = sp1l + (i0 * 9 + bp) * 16 + s_a;
            frag16 Ah, Al;
            Ah[0] = (short)hp[0];   Ah[1] = (short)hp[16];
            Ah[2] = (short)hp[48];  Ah[3] = (short)hp[64];
            Ah[4] = (short)hp[144]; Ah[5] = (short)hp[160];
            Ah[6] = (short)hp[192]; Ah[7] = (short)hp[208];
            Al[0] = (short)lp[0];   Al[1] = (short)lp[16];
            Al[2] = (short)lp[48];  Al[3] = (short)lp[64];
            Al[4] = (short)lp[144]; Al[5] = (short)lp[160];
            Al[6] = (short)lp[192]; Al[7] = (short)lp[208];
            frag16 W0h = *(const frag16*)(w2bh + u0 + k0);
            frag16 W0l = *(const frag16*)(w2bl + u0 + k0);
            frag16 W1h = *(const frag16*)(w2bh + u1 + k0);
            frag16 W1l = *(const frag16*)(w2bl + u1 + k0);
            acc0 = __builtin_amdgcn_mfma_f32_16x16x32_bf16(Ah, W0h, acc0, 0, 0, 0);
            acc0 = __builtin_amdgcn_mfma_f32_16x16x32_bf16(Al, W0h, acc0, 0, 0, 0);
            acc0 = __builtin_amdgcn_mfma_f32_16x16x32_bf16(Ah, W0l, acc0, 0, 0, 0);
            acc1 = __builtin_amdgcn_mfma_f32_16x16x32_bf16(Ah, W1h, acc1, 0, 0, 0);
            acc1 = __builtin_amdgcn_mfma_f32_16x16x32_bf16(Al, W1h, acc1, 0, 0, 0);
            acc1 = __builtin_amdgcn_mfma_f32_16x16x32_bf16(Ah, W1l, acc1, 0, 0, 0);
        }
        __syncthreads();   // all sp1 reads done; sA3 overlays sp1h front
        int sC = Mt * 4 + quad;
        #pragma unroll
        for (int nt = 0; nt < 2; nt++) {
            fragf4 a = nt ? acc1 : acc0;
            int o2 = (NtB + nt) * 16 + l16;
            float b = c2bF[o2];
            #pragma unroll
            for (int reg = 0; reg < 4; reg++) {
                float v = fmaxf(a[reg] + b, 0.f);
                unsigned short h, l;
                f2bf2(v, h, l);
                sA3h[sC * 264 + o2 * 4 + reg] = h;
                sA3l[sC * 264 + o2 * 4 + reg] = l;
            }
        }
    }
    __syncthreads();
    PHASE_FENCE();   // conv2 state dead; forbid w3/lwtb/Bf hoisting above

    // ---- conv3 MFMA: M=16 x N=128 x K=256; x -> sEh (bf16 RNE) ----
    {
        fragf4 acc0 = {0.f,0.f,0.f,0.f};
        int u0 = (wave * 16 + l16) * 256;
        #pragma unroll
        for (int kc = 0; kc < 8; kc++) {
            int k0 = kc * 32 + quad * 8;
            frag16 Ah = *(const frag16*)(sA3h + l16 * 264 + k0);
            frag16 Al = *(const frag16*)(sA3l + l16 * 264 + k0);
            frag16 W0h = *(const frag16*)(w3bh + u0 + k0);
            frag16 W0l = *(const frag16*)(w3bl + u0 + k0);
            acc0 = __builtin_amdgcn_mfma_f32_16x16x32_bf16(Ah, W0h, acc0, 0, 0, 0);
            acc0 = __builtin_amdgcn_mfma_f32_16x16x32_bf16(Al, W0h, acc0, 0, 0, 0);
            acc0 = __builtin_amdgcn_mfma_f32_16x16x32_bf16(Ah, W0l, acc0, 0, 0, 0);
        }
        int o3 = wave * 16 + l16;
        float b = c3bF[o3];
        #pragma unroll
        for (int reg = 0; reg < 4; reg++) {
            int s = quad * 4 + reg;
            sEh[s * 264 + o3] = f2bf(fmaxf(acc0[reg] + b, 0.f));
        }
    }
    __syncthreads();   // x + h staged in sEh
    PHASE_FENCE();     // conv3 state dead; forbid lwtb/Bf hoisting above

    // ---- LSTM MFMA: gates[16x512] = xa[16x256] @ lwtb^T ----
    {
        frag16 Ax[8];
        #pragma unroll
        for (int kc = 0; kc < 8; kc++)
            Ax[kc] = *(const frag16*)(sEh + l16 * 264 + kc * 32 + quad * 8);
        fragf4 aI = {0.f,0.f,0.f,0.f}, aF = {0.f,0.f,0.f,0.f};
        fragf4 aG = {0.f,0.f,0.f,0.f}, aO = {0.f,0.f,0.f,0.f};
        #pragma unroll
        for (int kc = 0; kc < 8; kc++) {
            int ko = kc * 32 + quad * 8;
            frag16 bI = *(const frag16*)(lwtb + (j)       * 256 + ko);
            frag16 bF = *(const frag16*)(lwtb + (128 + j) * 256 + ko);
            frag16 bG = *(const frag16*)(lwtb + (256 + j) * 256 + ko);
            frag16 bO = *(const frag16*)(lwtb + (384 + j) * 256 + ko);
            aI = __builtin_amdgcn_mfma_f32_16x16x32_bf16(Ax[kc], bI, aI, 0, 0, 0);
            aF = __builtin_amdgcn_mfma_f32_16x16x32_bf16(Ax[kc], bF, aF, 0, 0, 0);
            aG = __builtin_amdgcn_mfma_f32_16x16x32_bf16(Ax[kc], bG, aG, 0, 0, 0);
            aO = __builtin_amdgcn_mfma_f32_16x16x32_bf16(Ax[kc], bO, aO, 0, 0, 0);
        }
        float lbI = lbF[j], lbFg = lbF[128 + j], lbG = lbF[256 + j], lbO = lbF[384 + j];
        __syncthreads();   // all sEh (xa) fragment reads complete
        #pragma unroll
        for (int reg = 0; reg < 4; reg++) {
            int m = m0 + reg;
            float ig = sigm(aI[reg] + lbI);
            float fg = sigm(aF[reg] + lbFg);
            float gv = tanh_f(aG[reg] + lbG);
            float og = sigm(aO[reg] + lbO);
            float cv = bfin ? bf2f(mem16[(rbase + m) * 256 + 128 + j])
                            : memf[(rbase + m) * 256 + 128 + j];
            float cn = fg * cv + ig * gv;
            float hn = og * tanh_f(cn);
            mem_out[(rbase + m) * 256 + j]       = hn;
            mem_out[(rbase + m) * 256 + 128 + j] = cn;
            unsigned short hh = f2bf(hn);
            sEh[m * 264 + j] = hh;                      // emb hi, k<128
            sEl[m * 264 + j] = f2bf(hn - bf2f(hh));     // emb lo residual
        }
    }
    PHASE_FENCE();     // LSTM state dead; scan-phase loads start here
    // zero sHt ping-pong (overlays dead conv scratch)
    for (int i = tid; i < 2176; i += 512) { sHtA[i] = 0; sHtB[i] = 0; }

    // ---- GRU B-frags (resident across scan; VGPR cap 128 keeps them) ----
    frag16 Bf0[4], Bf1[4], Bf2[4];
    #pragma unroll
    for (int kc = 0; kc < 4; kc++) {
        int ko = kc * 32 + quad * 8;
        Bf0[kc] = *(const frag16*)(whb2 + (j)       * 128 + ko);
        Bf1[kc] = *(const frag16*)(whb2 + (128 + j) * 128 + ko);
        Bf2[kc] = *(const frag16*)(whb2 + (256 + j) * 128 + ko);
    }
    float bh0 = bhF[j], bh1 = bhF[128 + j], bh2 = bhF[256 + j];
    float hpv[4] = { 0.f, 0.f, 0.f, 0.f };
    float ga[12], gb[12];

    GI_LOAD(ga, 0);
    __syncthreads();   // sHt zeros visible before first A-frag read

    // ---- scan: 1 barrier/step, ping-pong sHt, gi prefetched across barrier ----
    for (int tt = 0; tt < 10; tt++) {
        int t0 = tt * 2;
        GRU_STEP(sHtA, sHtB, ga, gb, t0);
        GRU_STEP(sHtB, sHtA, gb, ga, t0 + 1);
    }

    // ---- emb stage k>=128: gru h from regs (exact bf16; El zero there) ----
    #pragma unroll
    for (int reg = 0; reg < 4; reg++) {
        int m = m0 + reg;
        sEh[m * 264 + 128 + j] = f2bf(hpv[reg]);
    }
    __syncthreads();

    // ---- head GEMM1 on MFMA: bf16 hi+lo split; El-skip for k>=128 ----
    fragf4 acc[4];
    {
        fragf4 z4 = {0.f,0.f,0.f,0.f};
        #pragma unroll
        for (int jb = 0; jb < 4; jb++) acc[jb] = z4;
        #pragma unroll
        for (int kc = 0; kc < 8; kc++) {
            int ko = kc * 32 + quad * 8;
            frag16 Eh = *(const frag16*)(sEh + l16 * 264 + ko);
            #pragma unroll
            for (int jb = 0; jb < 4; jb++) {
                int u = jb * 128 + wave * 16 + l16;
                frag16 Wh = *(const frag16*)(wtbh + u * 256 + ko);
                frag16 Wl = *(const frag16*)(wtbl + u * 256 + ko);
                acc[jb] = __builtin_amdgcn_mfma_f32_16x16x32_bf16(Eh, Wh, acc[jb], 0, 0, 0);
                acc[jb] = __builtin_amdgcn_mfma_f32_16x16x32_bf16(Eh, Wl, acc[jb], 0, 0, 0);
            }
            if (kc < 4) {
                frag16 El = *(const frag16*)(sEl + l16 * 264 + ko);
                #pragma unroll
                for (int jb = 0; jb < 4; jb++) {
                    int u = jb * 128 + wave * 16 + l16;
                    frag16 Wh = *(const frag16*)(wtbh + u * 256 + ko);
                    acc[jb] = __builtin_amdgcn_mfma_f32_16x16x32_bf16(El, Wh, acc[jb], 0, 0, 0);
                }
            }
        }
    }
    __syncthreads();   // sHt/conv scratch dead; sHid overlay becomes live

    // ---- write hidden [512u][16m] swizzled ----
    #pragma unroll
    for (int jb = 0; jb < 4; jb++) {
        int u = jb * 128 + wave * 16 + l16;
        float bu = b1F[u];
        #pragma unroll
        for (int reg = 0; reg < 4; reg++) {
            int m = m0 + reg;
            sHid[u * 16 + ((m + l16) & 15)] = tanh_f(acc[jb][reg] + bu);
        }
    }
    __syncthreads();

    // ---- GEMM2: 512 threads, 4 per output (r,i); shfl_xor reduce ----
    {
        int out = tid >> 2, kq = tid & 3;
        int r = out >> 3, i = out & 7;
        const float* wrp = W2f + i * 256;
        int ubase = (i < 7) ? 0 : 256;
        float ps = 0.f;
        int kb = kq * 64;
        for (int kk = 0; kk < 64; kk++) {
            int u = ubase + kb + kk;
            ps += wrp[kb + kk] * sHid[u * 16 + ((r + (u & 15)) & 15)];
        }
        ps += __shfl_xor(ps, 1);
        ps += __shfl_xor(ps, 2);
        if (kq == 0) sScore[out] = ps + B2f[i];
    }
    __syncthreads();

    // ---- softmax + outputs (128 threads) ----
    if (tid < 128) {
        int r = tid >> 3, i = tid & 7;
        float sc = sScore[tid];
        const float* sr = sScore + r * 8;
        float mx = sr[0];
        #pragma unroll
        for (int a = 1; a < 7; a++) mx = fmaxf(mx, sr[a]);
        float se = 0.f;
        #pragma unroll
        for (int a = 0; a < 7; a++) se += __expf(sr[a] - mx);
        float lse = mx + __logf(se);
        if (i < 7) out_lp[(rbase + r) * 7 + i] = sc - lse;
        else       out_val[rbase + r] = sc;
    }
}

// ======================================================================
extern "C" void kernel_launch(void* const* d_in, const int* in_sizes, int n_in,
                              void* d_out, int out_size, void* d_ws, size_t ws_size,
                              hipStream_t stream) {
    const int*  image  = (const int*)d_in[0];
    const void* memory = d_in[1];
    const int*  text   = (const int*)d_in[2];

    char* wsb = (char*)d_ws;
    float* ws0  = (float*)wsb;
    int*   flag = (int*)(wsb + WS_FLAG);

    float* out = (float*)d_out;
    float* out_lp  = out;
    float* out_val = out + OUT_VAL_OFF;
    float* mem_out = out + OUT_MEM_OFF;

    sniff_kernel<<<1, 256, 0, stream>>>((const unsigned short*)d_in[16], flag);

    const int PREP_GRID = (PREP_TASKS + 255) / 256;
    prep_kernel<true><<<PREP_GRID, 256, 0, stream>>>(flag,
        d_in[16], d_in[17], d_in[19], d_in[4], d_in[3], d_in[5],
        d_in[6], d_in[7], d_in[8], d_in[9], d_in[10], d_in[11],
        d_in[12], d_in[13], d_in[14], d_in[15],
        d_in[21], d_in[22], d_in[23], d_in[24],
        d_in[25], d_in[26], d_in[27], d_in[28],
        d_in[18], d_in[20], ws0);
    prep_kernel<false><<<PREP_GRID, 256, 0, stream>>>(flag,
        d_in[16], d_in[17], d_in[19], d_in[4], d_in[3], d_in[5],
        d_in[6], d_in[7], d_in[8], d_in[9], d_in[10], d_in[11],
        d_in[12], d_in[13], d_in[14], d_in[15],
        d_in[21], d_in[22], d_in[23], d_in[24],
        d_in[25], d_in[26], d_in[27], d_in[28],
        d_in[18], d_in[20], ws0);

    gru_head_kernel<<<GBLK, 512, 0, stream>>>(flag, image, text, memory, ws0,
                                              mem_out, out_lp, out_val);
}

// Round 9
// 259.601 us; speedup vs baseline: 1.0388x; 1.0113x over previous
//
#include <hip/hip_runtime.h>

// ---------- constants ----------
#define Bsz   8192
#define Tlen  20
#define OUT_VAL_OFF  57344      // 8192*7 (floats)
#define OUT_MEM_OFF  65536      // +8192  (floats)

// ws layout (bytes)
#define WS_GI     0            // float[100*384]  gi_table[v][g]
#define WS_D1     153600       // float[8*2*2*64] conv1 lookup (bank-rotated)
#define WS_W2BH   161792       // ushort[64*256]  bf16-hi conv2 w [o2][i*4+dp]
#define WS_W2BL   194560       // ushort[64*256]  bf16-lo residual
#define WS_W3BH   227328       // ushort[128*256] bf16-hi conv3 w [o3][o2*4+p2]
#define WS_W3BL   292864       // ushort[128*256] bf16-lo residual
#define WS_WHF    686080       // legacy (unused)
#define WS_WTBH   882688       // ushort[512*256] bf16-hi head W1 [u][k]
#define WS_WTBL   1144832      // ushort[512*256] bf16-lo residual [u][k]
#define WS_LB     1406976      // float[512]  (bih+bhh)
#define WS_C2W    1409024      // float[16384]  legacy fp32 c2wT (unused)
#define WS_C2B    1474560      // float[64]
#define WS_C3W    1474816      // float[32768]  legacy fp32 c3wT (unused)
#define WS_C3B    1605888      // float[128]
#define WS_C1B    1606400      // float[64]
#define WS_BH     1606656      // float[384]  gru_bhh
#define WS_B1     1608192      // float[512]
#define WS_W2     1610240      // float[8*256]
#define WS_B2     1618432      // float[8]
#define WS_FLAG   1618464      // int
#define WS_WHB    1618496      // ushort[384*128] bf16 whh[g][k] (GRU MFMA B)
#define WS_LWTB   1716800      // ushort[512*256] bf16 lstm [g][k] k<128 wih else whh

#define GBLK   512             // blocks (16 samples each)
#define GROWS  16              // samples per block
#define PREP_TASKS 453768

// phase fence (scheduler-level; harmless)
#define PHASE_FENCE() __builtin_amdgcn_sched_barrier(0)
// opaque pointer launder: creates a data dependence no IR pass or
// scheduler can hoist loads across (r7 lesson: sched_barrier alone does
// NOT stop IR-level LICM/GVN hoisting -> 60MB/side scratch spill).
// Implemented via u64 round-trip for maximum toolchain robustness.
#define LAUNDER(p) do {                                                \
    unsigned long long _lp = (unsigned long long)(p);                  \
    asm volatile("" : "+s"(_lp));                                      \
    (p) = (decltype(p))_lp;                                            \
} while (0)

// MFMA fragment types
using frag16 = __attribute__((ext_vector_type(8))) short;   // 8 bf16 (4 VGPRs)
using fragf4 = __attribute__((ext_vector_type(4))) float;   // 4 fp32

// ---------- helpers ----------
__device__ __forceinline__ float bf2f(unsigned short u){
    union { unsigned int i; float f; } v; v.i = ((unsigned int)u) << 16; return v.f;
}
__device__ __forceinline__ unsigned short f2bf(float f){
    union { float f; unsigned int i; } v; v.f = f;
    unsigned int x = v.i;
    return (unsigned short)((x + 0x7fffu + ((x >> 16) & 1u)) >> 16);
}
// truncation hi + RNE lo split (fp32 ~= hi + lo to 2^-17 rel)
__device__ __forceinline__ void f2bf2(float f, unsigned short &h, unsigned short &l){
    union { float f; unsigned int i; } u; u.f = f;
    h = (unsigned short)(u.i >> 16);
    union { unsigned int i; float f; } t; t.i = u.i & 0xffff0000u;
    l = f2bf(f - t.f);
}
__device__ __forceinline__ float sigm(float x){ return 1.0f / (1.0f + __expf(-x)); }
__device__ __forceinline__ float tanh_f(float x){ return 1.0f - 2.0f / (__expf(2.0f * x) + 1.0f); }

template<bool BF>
__device__ __forceinline__ float G(const void* p, int i){
    if (BF) return bf2f(((const unsigned short*)p)[i]);
    else    return ((const float*)p)[i];
}

// ======================================================================
// dtype sniff (verified across r1-13)
// ======================================================================
__global__ __launch_bounds__(256) void sniff_kernel(
    const unsigned short* __restrict__ we, int* __restrict__ flag)
{
    __shared__ int cnt;
    if (threadIdx.x == 0) cnt = 0;
    __syncthreads();
    int c = 0;
    for (int i = threadIdx.x; i < 2048; i += 256) {
        int e = (we[i] >> 7) & 0xFF;
        if (e >= 96 && e <= 160) c++;
    }
    atomicAdd(&cnt, c);
    __syncthreads();
    if (threadIdx.x == 0) *flag = (cnt >= 1792) ? 1 : 0;
}

// ======================================================================
// prep: canonicalize + fused/transposed tables. 453768 tasks.
// ======================================================================
template<bool BF>
__global__ __launch_bounds__(256) void prep_kernel(
    const int* __restrict__ flag,
    const void* word_emb, const void* gru_wih, const void* gru_bih,
    const void* col_emb, const void* obj_emb, const void* st_emb,
    const void* conv1_w, const void* conv1_b,
    const void* conv2_w, const void* conv2_b,
    const void* conv3_w, const void* conv3_b,
    const void* lstm_wih, const void* lstm_whh,
    const void* lstm_bih, const void* lstm_bhh,
    const void* actor_w1, const void* actor_b1,
    const void* actor_w2, const void* actor_b2,
    const void* critic_w1, const void* critic_b1,
    const void* critic_w2, const void* critic_b2,
    const void* gru_whh, const void* gru_bhh,
    float* __restrict__ ws0)
{
    if ((*flag != 0) != BF) return;
    int task = blockIdx.x * 256 + threadIdx.x;
    if (task >= PREP_TASKS) return;
    char* wsb = (char*)ws0;
    if (task < 38400) {
        int v = task / 384, g = task - v * 384;
        float acc = G<BF>(gru_bih, g);
        #pragma unroll
        for (int d = 0; d < 32; d++)
            acc += G<BF>(word_emb, v * 32 + d) * G<BF>(gru_wih, g * 32 + d);
        ((float*)(wsb + WS_GI))[task] = acc;
    } else if (task < 40448) {
        int i2 = task - 38400;
        int o = i2 & 63; int tkk = i2 >> 6;
        int kx = tkk & 1, ky = (tkk >> 1) & 1, t = tkk >> 2;
        int c = t & 1, ob = (t >> 1) & 1, s = (t >> 2) & 1;
        float acc = 0.f;
        #pragma unroll
        for (int i = 0; i < 48; i++) {
            float e;
            if (i < 16)      e = G<BF>(col_emb, c * 16 + i);
            else if (i < 32) e = G<BF>(obj_emb, ob * 16 + (i - 16));
            else             e = G<BF>(st_emb, s * 16 + (i - 32));
            acc += e * G<BF>(conv1_w, ((o * 48 + i) * 2 + ky) * 2 + kx);
        }
        ((float*)(wsb + WS_D1))[tkk * 64 + ((o + tkk) & 63)] = acc;  // rotated
    } else if (task < 171520) {
        int i3 = task - 40448;                 // head W1 bf16 hi/lo [u][k]
        int u = i3 >> 8, k = i3 & 255;
        float w = (u < 256) ? G<BF>(actor_w1, u * 256 + k)
                            : G<BF>(critic_w1, (u - 256) * 256 + k);
        unsigned short hi = f2bf(w);
        ((unsigned short*)(wsb + WS_WTBH))[i3] = hi;
        ((unsigned short*)(wsb + WS_WTBL))[i3] = f2bf(w - bf2f(hi));
    } else if (task < 172032) {
        int i = task - 171520;
        ((float*)(wsb + WS_LB))[i] = G<BF>(lstm_bih, i) + G<BF>(lstm_bhh, i);
    } else if (task < 188416) {
        int i = task - 172032;                 // legacy c2wT (unused)
        int o = i & 63, pp = (i >> 6) & 3, ii = i >> 8;
        ((float*)(wsb + WS_C2W))[i] = G<BF>(conv2_w, o * 256 + ii * 4 + pp);
    } else if (task < 188480) {
        int i = task - 188416;
        ((float*)(wsb + WS_C2B))[i] = G<BF>(conv2_b, i);
    } else if (task < 221248) {
        int i = task - 188480;                 // legacy c3wT (unused)
        int o = i & 127, kk = i >> 7;
        ((float*)(wsb + WS_C3W))[i] = G<BF>(conv3_w, o * 256 + kk);
    } else if (task < 221376) {
        int i = task - 221248;
        ((float*)(wsb + WS_C3B))[i] = G<BF>(conv3_b, i);
    } else if (task < 221440) {
        int i = task - 221376;
        ((float*)(wsb + WS_C1B))[i] = G<BF>(conv1_b, i);
    } else if (task < 221824) {
        int i = task - 221440;
        ((float*)(wsb + WS_BH))[i] = G<BF>(gru_bhh, i);
    } else if (task < 222336) {
        int i = task - 221824;
        ((float*)(wsb + WS_B1))[i] = (i < 256) ? G<BF>(actor_b1, i) : G<BF>(critic_b1, i - 256);
    } else if (task < 224384) {
        int i = task - 222336;
        int u = i >> 8, k = i & 255;
        ((float*)(wsb + WS_W2))[i] = (u < 7) ? G<BF>(actor_w2, u * 256 + k) : G<BF>(critic_w2, k);
    } else if (task < 224392) {
        int i = task - 224384;
        ((float*)(wsb + WS_B2))[i] = (i < 7) ? G<BF>(actor_b2, i) : G<BF>(critic_b2, 0);
    } else if (task < 273544) {
        int i = task - 224392;                 // WHB2: bf16 whh[g][k], row-major
        ((unsigned short*)(wsb + WS_WHB))[i] = f2bf(G<BF>(gru_whh, i));
    } else if (task < 404616) {
        int i = task - 273544;                 // LWTB: bf16 lstm [g][k]
        int g = i >> 8, k = i & 255;
        float v = (k < 128) ? G<BF>(lstm_wih, g * 128 + k)
                            : G<BF>(lstm_whh, g * 128 + (k - 128));
        ((unsigned short*)(wsb + WS_LWTB))[i] = f2bf(v);
    } else if (task < 421000) {
        int i = task - 404616;                 // conv2 w hi/lo [o2][i*4+dp]
        float w = G<BF>(conv2_w, i);
        unsigned short hi = f2bf(w);
        ((unsigned short*)(wsb + WS_W2BH))[i] = hi;
        ((unsigned short*)(wsb + WS_W2BL))[i] = f2bf(w - bf2f(hi));
    } else {
        int i = task - 421000;                 // conv3 w hi/lo [o3][o2*4+p2]
        float w = G<BF>(conv3_w, i);
        unsigned short hi = f2bf(w);
        ((unsigned short*)(wsb + WS_W3BH))[i] = hi;
        ((unsigned short*)(wsb + WS_W3BL))[i] = f2bf(w - bf2f(hi));
    }
}

// ======================================================================
// fused kernel v14b: conv1/2/3 + LSTM + GRU scan + heads, one launch.
// v13 + opaque pointer laundering per phase (u64 round-trip form).
// ======================================================================
#define GI_LOAD(dst, t) do {                                                  \
    _Pragma("unroll")                                                         \
    for (int rg_ = 0; rg_ < 4; rg_++) {                                       \
        int tok_ = sTok2[(m0 + rg_) * Tlen + (t)];                            \
        const float* gp_ = gi_tab + tok_ * 384 + j;                           \
        dst[rg_ * 3 + 0] = gp_[0];                                            \
        dst[rg_ * 3 + 1] = gp_[128];                                          \
        dst[rg_ * 3 + 2] = gp_[256];                                          \
    }                                                                         \
} while (0)

#define GRU_STEP(SRD, SWR, GC, GN, T) do {                                    \
    frag16 Af_[4];                                                            \
    _Pragma("unroll")                                                         \
    for (int kc_ = 0; kc_ < 4; kc_++)                                         \
        Af_[kc_] = *(const frag16*)((SRD) + l16 * 136 + kc_ * 32 + quad * 8); \
    fragf4 aR_ = {0.f,0.f,0.f,0.f}, aZ_ = {0.f,0.f,0.f,0.f};                  \
    fragf4 aN_ = {0.f,0.f,0.f,0.f};                                           \
    _Pragma("unroll")                                                         \
    for (int kc_ = 0; kc_ < 4; kc_++) {                                       \
        aR_ = __builtin_amdgcn_mfma_f32_16x16x32_bf16(Af_[kc_], Bf0[kc_], aR_, 0, 0, 0); \
        aZ_ = __builtin_amdgcn_mfma_f32_16x16x32_bf16(Af_[kc_], Bf1[kc_], aZ_, 0, 0, 0); \
        aN_ = __builtin_amdgcn_mfma_f32_16x16x32_bf16(Af_[kc_], Bf2[kc_], aN_, 0, 0, 0); \
    }                                                                         \
    if ((T) < Tlen - 1) GI_LOAD(GN, (T) + 1);                                 \
    _Pragma("unroll")                                                         \
    for (int reg_ = 0; reg_ < 4; reg_++) {                                    \
        float rg2_ = sigm(GC[reg_*3+0] + aR_[reg_] + bh0);                    \
        float zg_  = sigm(GC[reg_*3+1] + aZ_[reg_] + bh1);                    \
        float ng_  = tanh_f(GC[reg_*3+2] + rg2_ * (aN_[reg_] + bh2));         \
        float hn_  = (1.f - zg_) * ng_ + zg_ * hpv[reg_];                     \
        unsigned short hb_ = f2bf(hn_);                                       \
        hpv[reg_] = bf2f(hb_);                                                \
        (SWR)[(m0 + reg_) * 136 + j] = hb_;                                   \
    }                                                                         \
    __syncthreads();                                                          \
} while (0)

__global__ __launch_bounds__(512, 4) void gru_head_kernel(
    const int* __restrict__ flag,
    const int* __restrict__ image,
    const int* __restrict__ text, const void* memory,
    const float* __restrict__ ws0,
    float* __restrict__ mem_out,
    float* __restrict__ out_lp, float* __restrict__ out_val)
{
    const char* wsb = (const char*)ws0;
    const float* D1g      = (const float*)(wsb + WS_D1);
    const float* c1bF     = (const float*)(wsb + WS_C1B);
    const float* c2bF     = (const float*)(wsb + WS_C2B);
    const float* c3bF     = (const float*)(wsb + WS_C3B);
    const unsigned short* w2bh = (const unsigned short*)(wsb + WS_W2BH);
    const unsigned short* w2bl = (const unsigned short*)(wsb + WS_W2BL);
    const float* bhF      = (const float*)(wsb + WS_BH);
    const float* b1F      = (const float*)(wsb + WS_B1);
    const float* B2f      = (const float*)(wsb + WS_B2);
    const float* lbF      = (const float*)(wsb + WS_LB);

    // ---- LDS: persistent sEh/sEl + phase-overlaid region2 ----
    __shared__ __align__(16) char sU[16896 + 45840];
    __shared__ float sScore[128];
    __shared__ int   sTok2[320];

    unsigned short* sEh = (unsigned short*)sU;               // [16][264] 8448B
    unsigned short* sEl = (unsigned short*)(sU + 8448);      // [16][264] 8448B
    char* R2 = sU + 16896;
    unsigned char*  stt  = (unsigned char*)R2;               // 784B
    float*          sD1  = (float*)(R2 + 784);               // 8192B
    unsigned short* sp1h = (unsigned short*)(R2 + 8976);     // [576][16] 18432B
    unsigned short* sp1l = (unsigned short*)(R2 + 27408);    // 18432B
    unsigned short* sA3h = (unsigned short*)(R2 + 8976);     // [16][264] over sp1h
    unsigned short* sA3l = (unsigned short*)(R2 + 17424);    // [16][264]
    unsigned short* sHtA = (unsigned short*)R2;              // [16][136]
    unsigned short* sHtB = (unsigned short*)(R2 + 4352);
    float*          sHid = (float*)R2;                       // [512][16] 32768B

    int tid = threadIdx.x;
    int rbase = blockIdx.x * GROWS;
    int b0 = rbase;
    int wave = tid >> 6, lane = tid & 63;
    int quad = lane >> 4, l16 = lane & 15;
    int j = wave * 16 + l16;
    int m0 = quad * 4;
    const bool bfin = (*flag != 0);
    const unsigned short* mem16 = (const unsigned short*)memory;
    const float*          memf  = (const float*)memory;

    // ---- phase 0: stage tokens, h (k>=128 of emb), stt, sD1 ----
    if (tid < 320) sTok2[tid] = text[rbase * Tlen + tid];
    for (int i = tid; i < 2048; i += 512) {
        int m = i >> 7, k = i & 127;
        float v = bfin ? bf2f(mem16[(rbase + m) * 256 + k])
                       : memf[(rbase + m) * 256 + k];
        sEh[m * 264 + 128 + k] = f2bf(v);
    }
    for (int i = tid; i < 2048; i += 512) sD1[i] = D1g[i];
    for (int i = tid; i < 784; i += 512) {
        int s = i / 49, p = i - s * 49;
        int base = ((b0 + s) * 49 + p) * 3;
        stt[i] = (unsigned char)(image[base + 1] | (image[base] << 1) | (image[base + 2] << 2));
    }
    __syncthreads();

    // ---- conv1 (rotated-D1 lookup) + relu + pool -> sp1 hi/lo ----
    for (int task = tid; task < 9216; task += 512) {
        int s = task & 15;
        int op = task >> 4;
        int o = op / 9, p = op - o * 9;
        int py = p / 3, px = p - py * 3;
        float bo = c1bF[o];
        float mx = 0.f;
        #pragma unroll
        for (int dy = 0; dy < 2; dy++)
        #pragma unroll
        for (int dx = 0; dx < 2; dx++) {
            int y = 2 * py + dy, x = 2 * px + dx;
            float sum = bo;
            #pragma unroll
            for (int ky = 0; ky < 2; ky++)
            #pragma unroll
            for (int kx = 0; kx < 2; kx++) {
                int t = stt[s * 49 + (y + ky) * 7 + (x + kx)];
                int tkk = t * 4 + ky * 2 + kx;
                sum += sD1[tkk * 64 + ((o + tkk) & 63)];
            }
            mx = fmaxf(mx, sum);
        }
        unsigned short h, l;
        f2bf2(mx, h, l);
        sp1h[op * 16 + s] = h;
        sp1l[op * 16 + s] = l;
    }
    __syncthreads();

    // ---- conv2 MFMA: M=64 (s,p2) x N=64 x K=256 ----
    {
        int Mt  = wave >> 1;
        int NtB = (wave & 1) * 2;
        int s_a = Mt * 4 + (l16 >> 2);
        int p2  = l16 & 3;
        int bp  = 3 * (p2 >> 1) + (p2 & 1);
        fragf4 acc0 = {0.f,0.f,0.f,0.f}, acc1 = {0.f,0.f,0.f,0.f};
        int u0 = (NtB * 16 + l16) * 256;
        int u1 = u0 + 16 * 256;
        #pragma unroll
        for (int kc = 0; kc < 8; kc++) {
            int k0 = kc * 32 + quad * 8;
            int i0 = k0 >> 2;
            const unsigned short* hp = sp1h + (i0 * 9 + bp) * 16 + s_a;
            const unsigned short* lp = sp1l + (i0 * 9 + bp) * 16 + s_a;
            frag16 Ah, Al;
            Ah[0] = (short)hp[0];   Ah[1] = (short)hp[16];
            Ah[2] = (short)hp[48];  Ah[3] = (short)hp[64];
            Ah[4] = (short)hp[144]; Ah[5] = (short)hp[160];
            Ah[6] = (short)hp[192]; Ah[7] = (short)hp[208];
            Al[0] = (short)lp[0];   Al[1] = (short)lp[16];
            Al[2] = (short)lp[48];  Al[3] = (short)lp[64];
            Al[4] = (short)lp[144]; Al[5] = (short)lp[160];
            Al[6] = (short)lp[192]; Al[7] = (short)lp[208];
            frag16 W0h = *(const frag16*)(w2bh + u0 + k0);
            frag16 W0l = *(const frag16*)(w2bl + u0 + k0);
            frag16 W1h = *(const frag16*)(w2bh + u1 + k0);
            frag16 W1l = *(const frag16*)(w2bl + u1 + k0);
            acc0 = __builtin_amdgcn_mfma_f32_16x16x32_bf16(Ah, W0h, acc0, 0, 0, 0);
            acc0 = __builtin_amdgcn_mfma_f32_16x16x32_bf16(Al, W0h, acc0, 0, 0, 0);
            acc0 = __builtin_amdgcn_mfma_f32_16x16x32_bf16(Ah, W0l, acc0, 0, 0, 0);
            acc1 = __builtin_amdgcn_mfma_f32_16x16x32_bf16(Ah, W1h, acc1, 0, 0, 0);
            acc1 = __builtin_amdgcn_mfma_f32_16x16x32_bf16(Al, W1h, acc1, 0, 0, 0);
            acc1 = __builtin_amdgcn_mfma_f32_16x16x32_bf16(Ah, W1l, acc1, 0, 0, 0);
        }
        __syncthreads();   // all sp1 reads done; sA3 overlays sp1h front
        int sC = Mt * 4 + quad;
        #pragma unroll
        for (int nt = 0; nt < 2; nt++) {
            fragf4 a = nt ? acc1 : acc0;
            int o2 = (NtB + nt) * 16 + l16;
            float b = c2bF[o2];
            #pragma unroll
            for (int reg = 0; reg < 4; reg++) {
                float v = fmaxf(a[reg] + b, 0.f);
                unsigned short h, l;
                f2bf2(v, h, l);
                sA3h[sC * 264 + o2 * 4 + reg] = h;
                sA3l[sC * 264 + o2 * 4 + reg] = l;
            }
        }
    }
    __syncthreads();
    PHASE_FENCE();

    // ---- conv3 MFMA: M=16 x N=128 x K=256; x -> sEh (bf16 RNE) ----
    {
        const unsigned short* w3bh = (const unsigned short*)(wsb + WS_W3BH);
        const unsigned short* w3bl = (const unsigned short*)(wsb + WS_W3BL);
        LAUNDER(w3bh);
        LAUNDER(w3bl);
        fragf4 acc0 = {0.f,0.f,0.f,0.f};
        int u0 = (wave * 16 + l16) * 256;
        #pragma unroll
        for (int kc = 0; kc < 8; kc++) {
            int k0 = kc * 32 + quad * 8;
            frag16 Ah = *(const frag16*)(sA3h + l16 * 264 + k0);
            frag16 Al = *(const frag16*)(sA3l + l16 * 264 + k0);
            frag16 W0h = *(const frag16*)(w3bh + u0 + k0);
            frag16 W0l = *(const frag16*)(w3bl + u0 + k0);
            acc0 = __builtin_amdgcn_mfma_f32_16x16x32_bf16(Ah, W0h, acc0, 0, 0, 0);
            acc0 = __builtin_amdgcn_mfma_f32_16x16x32_bf16(Al, W0h, acc0, 0, 0, 0);
            acc0 = __builtin_amdgcn_mfma_f32_16x16x32_bf16(Ah, W0l, acc0, 0, 0, 0);
        }
        int o3 = wave * 16 + l16;
        float b = c3bF[o3];
        #pragma unroll
        for (int reg = 0; reg < 4; reg++) {
            int s = quad * 4 + reg;
            sEh[s * 264 + o3] = f2bf(fmaxf(acc0[reg] + b, 0.f));
        }
    }
    __syncthreads();   // x + h staged in sEh
    PHASE_FENCE();

    // ---- LSTM MFMA: gates[16x512] = xa[16x256] @ lwtb^T ----
    {
        const unsigned short* lwtb = (const unsigned short*)(wsb + WS_LWTB);
        LAUNDER(lwtb);
        frag16 Ax[8];
        #pragma unroll
        for (int kc = 0; kc < 8; kc++)
            Ax[kc] = *(const frag16*)(sEh + l16 * 264 + kc * 32 + quad * 8);
        fragf4 aI = {0.f,0.f,0.f,0.f}, aF = {0.f,0.f,0.f,0.f};
        fragf4 aG = {0.f,0.f,0.f,0.f}, aO = {0.f,0.f,0.f,0.f};
        #pragma unroll
        for (int kc = 0; kc < 8; kc++) {
            int ko = kc * 32 + quad * 8;
            frag16 bI = *(const frag16*)(lwtb + (j)       * 256 + ko);
            frag16 bF = *(const frag16*)(lwtb + (128 + j) * 256 + ko);
            frag16 bG = *(const frag16*)(lwtb + (256 + j) * 256 + ko);
            frag16 bO = *(const frag16*)(lwtb + (384 + j) * 256 + ko);
            aI = __builtin_amdgcn_mfma_f32_16x16x32_bf16(Ax[kc], bI, aI, 0, 0, 0);
            aF = __builtin_amdgcn_mfma_f32_16x16x32_bf16(Ax[kc], bF, aF, 0, 0, 0);
            aG = __builtin_amdgcn_mfma_f32_16x16x32_bf16(Ax[kc], bG, aG, 0, 0, 0);
            aO = __builtin_amdgcn_mfma_f32_16x16x32_bf16(Ax[kc], bO, aO, 0, 0, 0);
        }
        float lbI = lbF[j], lbFg = lbF[128 + j], lbG = lbF[256 + j], lbO = lbF[384 + j];
        __syncthreads();   // all sEh (xa) fragment reads complete
        #pragma unroll
        for (int reg = 0; reg < 4; reg++) {
            int m = m0 + reg;
            float ig = sigm(aI[reg] + lbI);
            float fg = sigm(aF[reg] + lbFg);
            float gv = tanh_f(aG[reg] + lbG);
            float og = sigm(aO[reg] + lbO);
            float cv = bfin ? bf2f(mem16[(rbase + m) * 256 + 128 + j])
                            : memf[(rbase + m) * 256 + 128 + j];
            float cn = fg * cv + ig * gv;
            float hn = og * tanh_f(cn);
            mem_out[(rbase + m) * 256 + j]       = hn;
            mem_out[(rbase + m) * 256 + 128 + j] = cn;
            unsigned short hh = f2bf(hn);
            sEh[m * 264 + j] = hh;                      // emb hi, k<128
            sEl[m * 264 + j] = f2bf(hn - bf2f(hh));     // emb lo residual
        }
    }
    PHASE_FENCE();
    // zero sHt ping-pong (overlays dead conv scratch)
    for (int i = tid; i < 2176; i += 512) { sHtA[i] = 0; sHtB[i] = 0; }

    // ---- scan phase: launder whb2 + gi_table, load B-frags ----
    const unsigned short* whb2 = (const unsigned short*)(wsb + WS_WHB);
    const float* gi_tab = (const float*)(wsb + WS_GI);
    LAUNDER(whb2);
    LAUNDER(gi_tab);
    frag16 Bf0[4], Bf1[4], Bf2[4];
    #pragma unroll
    for (int kc = 0; kc < 4; kc++) {
        int ko = kc * 32 + quad * 8;
        Bf0[kc] = *(const frag16*)(whb2 + (j)       * 128 + ko);
        Bf1[kc] = *(const frag16*)(whb2 + (128 + j) * 128 + ko);
        Bf2[kc] = *(const frag16*)(whb2 + (256 + j) * 128 + ko);
    }
    float bh0 = bhF[j], bh1 = bhF[128 + j], bh2 = bhF[256 + j];
    float hpv[4] = { 0.f, 0.f, 0.f, 0.f };
    float ga[12], gb[12];

    GI_LOAD(ga, 0);
    __syncthreads();   // sHt zeros visible before first A-frag read

    // ---- scan: 1 barrier/step, ping-pong sHt, gi prefetched across barrier ----
    for (int tt = 0; tt < 10; tt++) {
        int t0 = tt * 2;
        GRU_STEP(sHtA, sHtB, ga, gb, t0);
        GRU_STEP(sHtB, sHtA, gb, ga, t0 + 1);
    }

    // ---- emb stage k>=128: gru h from regs (exact bf16; El zero there) ----
    #pragma unroll
    for (int reg = 0; reg < 4; reg++) {
        int m = m0 + reg;
        sEh[m * 264 + 128 + j] = f2bf(hpv[reg]);
    }
    __syncthreads();
    PHASE_FENCE();

    // ---- head GEMM1 on MFMA: bf16 hi+lo split; El-skip for k>=128 ----
    fragf4 acc[4];
    {
        const unsigned short* wtbh = (const unsigned short*)(wsb + WS_WTBH);
        const unsigned short* wtbl = (const unsigned short*)(wsb + WS_WTBL);
        LAUNDER(wtbh);
        LAUNDER(wtbl);
        fragf4 z4 = {0.f,0.f,0.f,0.f};
        #pragma unroll
        for (int jb = 0; jb < 4; jb++) acc[jb] = z4;
        #pragma unroll
        for (int kc = 0; kc < 8; kc++) {
            int ko = kc * 32 + quad * 8;
            frag16 Eh = *(const frag16*)(sEh + l16 * 264 + ko);
            #pragma unroll
            for (int jb = 0; jb < 4; jb++) {
                int u = jb * 128 + wave * 16 + l16;
                frag16 Wh = *(const frag16*)(wtbh + u * 256 + ko);
                frag16 Wl = *(const frag16*)(wtbl + u * 256 + ko);
                acc[jb] = __builtin_amdgcn_mfma_f32_16x16x32_bf16(Eh, Wh, acc[jb], 0, 0, 0);
                acc[jb] = __builtin_amdgcn_mfma_f32_16x16x32_bf16(Eh, Wl, acc[jb], 0, 0, 0);
            }
            if (kc < 4) {
                frag16 El = *(const frag16*)(sEl + l16 * 264 + ko);
                #pragma unroll
                for (int jb = 0; jb < 4; jb++) {
                    int u = jb * 128 + wave * 16 + l16;
                    frag16 Wh = *(const frag16*)(wtbh + u * 256 + ko);
                    acc[jb] = __builtin_amdgcn_mfma_f32_16x16x32_bf16(El, Wh, acc[jb], 0, 0, 0);
                }
            }
        }
    }
    __syncthreads();   // sHt/conv scratch dead; sHid overlay becomes live

    // ---- write hidden [512u][16m] swizzled ----
    #pragma unroll
    for (int jb = 0; jb < 4; jb++) {
        int u = jb * 128 + wave * 16 + l16;
        float bu = b1F[u];
        #pragma unroll
        for (int reg = 0; reg < 4; reg++) {
            int m = m0 + reg;
            sHid[u * 16 + ((m + l16) & 15)] = tanh_f(acc[jb][reg] + bu);
        }
    }
    __syncthreads();

    // ---- GEMM2: 512 threads, 4 per output (r,i); shfl_xor reduce ----
    {
        const float* W2f = (const float*)(wsb + WS_W2);
        LAUNDER(W2f);
        int out = tid >> 2, kq = tid & 3;
        int r = out >> 3, i = out & 7;
        const float* wrp = W2f + i * 256;
        int ubase = (i < 7) ? 0 : 256;
        float ps = 0.f;
        int kb = kq * 64;
        for (int kk = 0; kk < 64; kk++) {
            int u = ubase + kb + kk;
            ps += wrp[kb + kk] * sHid[u * 16 + ((r + (u & 15)) & 15)];
        }
        ps += __shfl_xor(ps, 1);
        ps += __shfl_xor(ps, 2);
        if (kq == 0) sScore[out] = ps + B2f[i];
    }
    __syncthreads();

    // ---- softmax + outputs (128 threads) ----
    if (tid < 128) {
        int r = tid >> 3, i = tid & 7;
        float sc = sScore[tid];
        const float* sr = sScore + r * 8;
        float mx = sr[0];
        #pragma unroll
        for (int a = 1; a < 7; a++) mx = fmaxf(mx, sr[a]);
        float se = 0.f;
        #pragma unroll
        for (int a = 0; a < 7; a++) se += __expf(sr[a] - mx);
        float lse = mx + __logf(se);
        if (i < 7) out_lp[(rbase + r) * 7 + i] = sc - lse;
        else       out_val[rbase + r] = sc;
    }
}

// ======================================================================
extern "C" void kernel_launch(void* const* d_in, const int* in_sizes, int n_in,
                              void* d_out, int out_size, void* d_ws, size_t ws_size,
                              hipStream_t stream) {
    const int*  image  = (const int*)d_in[0];
    const void* memory = d_in[1];
    const int*  text   = (const int*)d_in[2];

    char* wsb = (char*)d_ws;
    float* ws0  = (float*)wsb;
    int*   flag = (int*)(wsb + WS_FLAG);

    float* out = (float*)d_out;
    float* out_lp  = out;
    float* out_val = out + OUT_VAL_OFF;
    float* mem_out = out + OUT_MEM_OFF;

    sniff_kernel<<<1, 256, 0, stream>>>((const unsigned short*)d_in[16], flag);

    const int PREP_GRID = (PREP_TASKS + 255) / 256;
    prep_kernel<true><<<PREP_GRID, 256, 0, stream>>>(flag,
        d_in[16], d_in[17], d_in[19], d_in[4], d_in[3], d_in[5],
        d_in[6], d_in[7], d_in[8], d_in[9], d_in[10], d_in[11],
        d_in[12], d_in[13], d_in[14], d_in[15],
        d_in[21], d_in[22], d_in[23], d_in[24],
        d_in[25], d_in[26], d_in[27], d_in[28],
        d_in[18], d_in[20], ws0);
    prep_kernel<false><<<PREP_GRID, 256, 0, stream>>>(flag,
        d_in[16], d_in[17], d_in[19], d_in[4], d_in[3], d_in[5],
        d_in[6], d_in[7], d_in[8], d_in[9], d_in[10], d_in[11],
        d_in[12], d_in[13], d_in[14], d_in[15],
        d_in[21], d_in[22], d_in[23], d_in[24],
        d_in[25], d_in[26], d_in[27], d_in[28],
        d_in[18], d_in[20], ws0);

    gru_head_kernel<<<GBLK, 512, 0, stream>>>(flag, image, text, memory, ws0,
                                              mem_out, out_lp, out_val);
}